// Round 6
// baseline (166.031 us; speedup 1.0000x reference)
//
#include <hip/hip_runtime.h>

// Problem constants (fixed by setup_inputs)
static constexpr int B_ = 256;
static constexpr int T_ = 16384;
static constexpr int TPB = 1024;                 // 16 waves; one block per batch row
static constexpr int F4_ROW = T_ * 2 / 4;        // 8192 float4 per b-row
static constexpr int F4_THR = F4_ROW / TPB;      // 8 consecutive float4 per thread

static constexpr float DTc    = 0.01f;
static constexpr float MINVAR = 0.01f;
static constexpr float EPSc   = 1e-6f;

// ws layout: float pPos[256], pLve[256], pLc[256], pReg[256]  (4 KB total)

__device__ __forceinline__ float waveReduce(float v) {
#pragma unroll
  for (int d = 32; d > 0; d >>= 1) v += __shfl_down(v, d, 64);
  return v;
}
__device__ __forceinline__ double waveReduceD(double v) {
#pragma unroll
  for (int d = 32; d > 0; d >>= 1) v += __shfl_down(v, d, 64);
  return v;
}

// One block per batch row; single pass; ONE barrier for the whole scan.
// Thread t owns float4 range [8t, 8t+8): local serial prefix -> wave scan of
// thread totals -> LDS wave totals -> barrier -> 16-entry shfl scan -> offsets.
__global__ __launch_bounds__(TPB) void fusedKern(
    const float4* __restrict__ vel, const float4* __restrict__ cov,
    const float4* __restrict__ vgt, const float4* __restrict__ pgt,
    float* __restrict__ pPos, float* __restrict__ pLve,
    float* __restrict__ pLc,  float* __restrict__ pReg) {
  const int b = blockIdx.x;
  const int tid = threadIdx.x;
  const int lane = tid & 63, wid = tid >> 6;           // 16 waves
  const int tbase = b * F4_ROW + tid * F4_THR;

  // ---- vel: load, thread-local exclusive prefix, keep only x/y for MSE ----
  float4 v[F4_THR];
#pragma unroll
  for (int j = 0; j < F4_THR; ++j) v[j] = vel[tbase + j];

  float ex[F4_THR], ey[F4_THR];                        // thread-local exclusive prefix
  float vx[F4_THR], vy[F4_THR];                        // first-timestep vel of each float4
  float tx = 0.f, ty = 0.f;
#pragma unroll
  for (int j = 0; j < F4_THR; ++j) {
    ex[j] = tx; ey[j] = ty;
    vx[j] = v[j].x; vy[j] = v[j].y;
    tx += v[j].x + v[j].z;
    ty += v[j].y + v[j].w;
  }

  // ---- elementwise stats (vel diff vs vgt, cov-based terms) ----
  float lve = 0.f, lc = 0.f, reg = 0.f;
#pragma unroll
  for (int j = 0; j < F4_THR; ++j) {
    float4 c = cov[tbase + j];
    float4 g = vgt[tbase + j];
    {
      float dx = g.x - v[j].x, dy = g.y - v[j].y;
      float sqx = dx * dx, sqy = dy * dy;
      lve += sqx + sqy;
      float sx = fmaxf(__expf(c.x), MINVAR);
      float sy = fmaxf(__expf(c.y), MINVAR);
      float ixv = 1.0f / sx, iyv = 1.0f / sy;
      lc += ixv * sqx + iyv * sqy + __logf(sx * sy + EPSc);
      reg += ixv + iyv;
    }
    {
      float dx = g.z - v[j].z, dy = g.w - v[j].w;
      float sqx = dx * dx, sqy = dy * dy;
      lve += sqx + sqy;
      float sx = fmaxf(__expf(c.z), MINVAR);
      float sy = fmaxf(__expf(c.w), MINVAR);
      float ixv = 1.0f / sx, iyv = 1.0f / sy;
      lc += ixv * sqx + iyv * sqy + __logf(sx * sy + EPSc);
      reg += ixv + iyv;
    }
  }

  // ---- wave inclusive scan of thread totals ----
  float sx = tx, sy = ty;
#pragma unroll
  for (int d = 1; d < 64; d <<= 1) {
    float ux = __shfl_up(sx, (unsigned)d, 64);
    float uy = __shfl_up(sy, (unsigned)d, 64);
    if (lane >= d) { sx += ux; sy += uy; }
  }
  const float wxx = sx - tx, wxy = sy - ty;            // wave-exclusive offset

  __shared__ float2 wt[16];
  __shared__ float  sh[4][16];
  if (lane == 63) wt[wid] = make_float2(sx, sy);
  __syncthreads();                                     // the ONE scan barrier

  // ---- cross-wave: 16-entry scan done with shuffles, then broadcast ----
  float ax = (lane < 16) ? wt[lane].x : 0.f;
  float ay = (lane < 16) ? wt[lane].y : 0.f;
  float iax = ax, iay = ay;
#pragma unroll
  for (int d = 1; d < 16; d <<= 1) {
    float ux = __shfl_up(iax, (unsigned)d, 64);
    float uy = __shfl_up(iay, (unsigned)d, 64);
    if (lane >= d) { iax += ux; iay += uy; }
  }
  const float bx0 = __shfl(iax - ax, wid, 64);         // block-exclusive offset for my wave
  const float by0 = __shfl(iay - ay, wid, 64);

  const float2 v0 = ((const float2*)vel)[b * T_];

  // ---- position MSE (pgt loaded here; vel no longer fully held) ----
  float apos = 0.f;
#pragma unroll
  for (int j = 0; j < F4_THR; ++j) {
    float4 q = pgt[tbase + j];
    float px0 = bx0 + wxx + ex[j];                     // exclusive prefix (vel units)
    float py0 = by0 + wxy + ey[j];
    float px = DTc * (v0.x + px0), py = DTc * (v0.y + py0);
    float e0 = px - q.x, e1 = py - q.y;
    apos += e0 * e0 + e1 * e1;
    px = DTc * (v0.x + px0 + vx[j]); py = DTc * (v0.y + py0 + vy[j]);
    e0 = px - q.z; e1 = py - q.w;
    apos += e0 * e0 + e1 * e1;
  }

  // ---- block reduce the 4 stats ----
  float r0 = waveReduce(apos);
  float r1 = waveReduce(lve);
  float r2 = waveReduce(lc);
  float r3 = waveReduce(reg);
  if (lane == 0) { sh[0][wid] = r0; sh[1][wid] = r1; sh[2][wid] = r2; sh[3][wid] = r3; }
  __syncthreads();
  if (tid == 0) {
    float t0 = 0.f, t1 = 0.f, t2 = 0.f, t3 = 0.f;
#pragma unroll
    for (int w = 0; w < 16; ++w) { t0 += sh[0][w]; t1 += sh[1][w]; t2 += sh[2][w]; t3 += sh[3][w]; }
    pPos[b] = t0; pLve[b] = t1; pLc[b] = t2; pReg[b] = t3;
  }
}

__global__ __launch_bounds__(256) void kernC(
    const float* __restrict__ pPos, const float* __restrict__ pLve,
    const float* __restrict__ pLc,  const float* __restrict__ pReg,
    const float* __restrict__ pldv, const float* __restrict__ pldc,
    float* __restrict__ out) {
  const int tid = threadIdx.x;
  const int lane = tid & 63, wid = tid >> 6;
  double a0 = (double)pPos[tid];
  double a1 = (double)pLve[tid];
  double a2 = (double)pLc[tid];
  double a3 = (double)pReg[tid];
  a0 = waveReduceD(a0);
  a1 = waveReduceD(a1);
  a2 = waveReduceD(a2);
  a3 = waveReduceD(a3);
  __shared__ double sh[4][4];
  if (lane == 0) { sh[0][wid] = a0; sh[1][wid] = a1; sh[2][wid] = a2; sh[3][wid] = a3; }
  __syncthreads();
  if (tid == 0) {
    double pos_sq = sh[0][0] + sh[0][1] + sh[0][2] + sh[0][3];
    double vel_sq = sh[1][0] + sh[1][1] + sh[1][2] + sh[1][3];
    double lcs    = sh[2][0] + sh[2][1] + sh[2][2] + sh[2][3];
    double regs   = sh[3][0] + sh[3][1] + sh[3][2] + sh[3][3];
    const double NBT2 = (double)B_ * (double)T_ * 2.0;
    const double NBT  = (double)B_ * (double)T_;
    double lv  = (pos_sq + vel_sq) / NBT2;
    double lc  = 0.5 * lcs / NBT;
    double reg = regs / NBT;
    double ldv = (double)pldv[0], ldc = (double)pldc[0];
    double total = lv / (2.0 * exp(2.0 * ldv)) + lc / (2.0 * exp(2.0 * ldc))
                 + ldv + ldc + 0.01 * reg;
    out[0] = (float)total;
  }
}

extern "C" void kernel_launch(void* const* d_in, const int* in_sizes, int n_in,
                              void* d_out, int out_size, void* d_ws, size_t ws_size,
                              hipStream_t stream) {
  const float4* vel = (const float4*)d_in[0];
  const float4* cov = (const float4*)d_in[1];
  const float4* vgt = (const float4*)d_in[2];
  const float4* pgt = (const float4*)d_in[3];
  const float* ldv = (const float*)d_in[4];
  const float* ldc = (const float*)d_in[5];

  char* ws = (char*)d_ws;
  float* pPos = (float*)ws;                 // 1 KB
  float* pLve = (float*)(ws + 1024);        // 1 KB
  float* pLc  = (float*)(ws + 2048);        // 1 KB
  float* pReg = (float*)(ws + 3072);        // 1 KB

  fusedKern<<<B_, TPB, 0, stream>>>(vel, cov, vgt, pgt, pPos, pLve, pLc, pReg);
  kernC<<<1, 256, 0, stream>>>(pPos, pLve, pLc, pReg, ldv, ldc, (float*)d_out);
}

// Round 8
// 155.311 us; speedup vs baseline: 1.0690x; 1.0690x over previous
//
#include <hip/hip_runtime.h>

// Problem constants (fixed by setup_inputs)
static constexpr int B_ = 256;
static constexpr int T_ = 16384;
static constexpr int THREADS = 256;              // 4 waves per block
static constexpr int SEG_T = 2048;               // timesteps per segment
static constexpr int NSEG = T_ / SEG_T;          // 8 segments per row
static constexpr int NBLK = B_ * NSEG;           // 2048 blocks
static constexpr int F4_ROW = T_ * 2 / 4;        // 8192 float4 per row
static constexpr int F4_SEG = SEG_T * 2 / 4;     // 1024 float4 per segment
static constexpr int F4_THR = F4_SEG / THREADS;  // 4 float4 per thread (consecutive)

static constexpr float DTc    = 0.01f;
static constexpr float MINVAR = 0.01f;
static constexpr float EPSc   = 1e-6f;

// ws layout (all written every call):
//   [0]     float2 segsum[NBLK]  16 KB   per-segment vel sums
//   [16KB]  float se2[NBLK]       8 KB   Sum e^2 (local-offset pos error, x+y)
//   [24KB]  float sex[NBLK]       8 KB   Sum e_x
//   [32KB]  float sey[NBLK]       8 KB   Sum e_y
//   [40KB]  float pLve[NBLK]      8 KB
//   [48KB]  float pLc [NBLK]      8 KB
//   [56KB]  float pReg[NBLK]      8 KB

__device__ __forceinline__ float waveReduce(float v) {
#pragma unroll
  for (int d = 32; d > 0; d >>= 1) v += __shfl_down(v, d, 64);
  return v;
}
__device__ __forceinline__ double waveReduceD(double v) {
#pragma unroll
  for (int d = 32; d > 0; d >>= 1) v += __shfl_down(v, d, 64);
  return v;
}

// One block per (row, segment). Single pass over all 4 arrays.
// Position error computed with segment-local prefix only; the unknown incoming
// prefix C is fixed up later via the quadratic identity:
//   sum((e + DT*C)^2) = sum(e^2) + 2*DT*(Cx*Sex + Cy*Sey) + n*DT^2*(Cx^2+Cy^2)
__global__ __launch_bounds__(THREADS) void kern1(
    const float4* __restrict__ vel, const float4* __restrict__ cov,
    const float4* __restrict__ vgt, const float4* __restrict__ pgt,
    float2* __restrict__ segsum, float* __restrict__ se2,
    float* __restrict__ sex, float* __restrict__ sey,
    float* __restrict__ pLve, float* __restrict__ pLc, float* __restrict__ pReg) {
  const int bid = blockIdx.x;
  const int b = bid >> 3, s = bid & (NSEG - 1);
  const int tid = threadIdx.x;
  const int lane = tid & 63, wid = tid >> 6;           // 4 waves
  const int tbase = b * F4_ROW + s * F4_SEG + tid * F4_THR;

  // ---- load everything (16 float4 = 64 regs of data; issues early) ----
  float4 v[F4_THR], c[F4_THR], g[F4_THR], q[F4_THR];
#pragma unroll
  for (int j = 0; j < F4_THR; ++j) v[j] = vel[tbase + j];
#pragma unroll
  for (int j = 0; j < F4_THR; ++j) c[j] = cov[tbase + j];
#pragma unroll
  for (int j = 0; j < F4_THR; ++j) g[j] = vgt[tbase + j];
#pragma unroll
  for (int j = 0; j < F4_THR; ++j) q[j] = pgt[tbase + j];

  // ---- thread-local exclusive prefix of vel (each float4 = 2 timesteps) ----
  float ex[F4_THR], ey[F4_THR];
  float tx = 0.f, ty = 0.f;
#pragma unroll
  for (int j = 0; j < F4_THR; ++j) {
    ex[j] = tx; ey[j] = ty;
    tx += v[j].x + v[j].z;
    ty += v[j].y + v[j].w;
  }

  // ---- wave inclusive scan of thread totals ----
  float sx = tx, sy = ty;
#pragma unroll
  for (int d = 1; d < 64; d <<= 1) {
    float ux = __shfl_up(sx, (unsigned)d, 64);
    float uy = __shfl_up(sy, (unsigned)d, 64);
    if (lane >= d) { sx += ux; sy += uy; }
  }
  const float wexx = sx - tx, wexy = sy - ty;          // wave-exclusive

  __shared__ float2 wt[4];
  if (lane == 63) wt[wid] = make_float2(sx, sy);
  __syncthreads();                                     // barrier 1 (scan)

  float offx = wexx, offy = wexy;                      // segment-local exclusive prefix base
  float segx = 0.f, segy = 0.f;
#pragma unroll
  for (int w = 0; w < 4; ++w) {
    float2 t = wt[w];
    if (w < wid) { offx += t.x; offy += t.y; }
    segx += t.x; segy += t.y;
  }

  const float2 v0 = ((const float2*)vel)[b * T_];      // row's first vel (broadcast)

  // ---- position error with LOCAL prefix only ----
  float ase2 = 0.f, asex = 0.f, asey = 0.f;
#pragma unroll
  for (int j = 0; j < F4_THR; ++j) {
    float px0 = offx + ex[j], py0 = offy + ey[j];      // excl prefix (vel units)
    float e0x = DTc * (v0.x + px0) - q[j].x;
    float e0y = DTc * (v0.y + py0) - q[j].y;
    float e1x = DTc * (v0.x + px0 + v[j].x) - q[j].z;
    float e1y = DTc * (v0.y + py0 + v[j].y) - q[j].w;
    ase2 += e0x * e0x + e0y * e0y + e1x * e1x + e1y * e1y;
    asex += e0x + e1x;
    asey += e0y + e1y;
  }

  // ---- elementwise stats ----
  float lve = 0.f, lc = 0.f, reg = 0.f;
#pragma unroll
  for (int j = 0; j < F4_THR; ++j) {
    {
      float dx = g[j].x - v[j].x, dy = g[j].y - v[j].y;
      float sqx = dx * dx, sqy = dy * dy;
      lve += sqx + sqy;
      float s0 = fmaxf(__expf(c[j].x), MINVAR);
      float s1 = fmaxf(__expf(c[j].y), MINVAR);
      float i0 = 1.0f / s0, i1 = 1.0f / s1;
      lc += i0 * sqx + i1 * sqy + __logf(s0 * s1 + EPSc);
      reg += i0 + i1;
    }
    {
      float dx = g[j].z - v[j].z, dy = g[j].w - v[j].w;
      float sqx = dx * dx, sqy = dy * dy;
      lve += sqx + sqy;
      float s0 = fmaxf(__expf(c[j].z), MINVAR);
      float s1 = fmaxf(__expf(c[j].w), MINVAR);
      float i0 = 1.0f / s0, i1 = 1.0f / s1;
      lc += i0 * sqx + i1 * sqy + __logf(s0 * s1 + EPSc);
      reg += i0 + i1;
    }
  }

  // ---- block reduce 6 partials ----
  float r0 = waveReduce(ase2);
  float r1 = waveReduce(asex);
  float r2 = waveReduce(asey);
  float r3 = waveReduce(lve);
  float r4 = waveReduce(lc);
  float r5 = waveReduce(reg);
  __shared__ float sh[6][4];
  if (lane == 0) { sh[0][wid] = r0; sh[1][wid] = r1; sh[2][wid] = r2;
                   sh[3][wid] = r3; sh[4][wid] = r4; sh[5][wid] = r5; }
  __syncthreads();                                     // barrier 2 (reduce)
  if (tid == 0) {
    segsum[bid] = make_float2(segx, segy);
    se2[bid] = sh[0][0] + sh[0][1] + sh[0][2] + sh[0][3];
    sex[bid] = sh[1][0] + sh[1][1] + sh[1][2] + sh[1][3];
    sey[bid] = sh[2][0] + sh[2][1] + sh[2][2] + sh[2][3];
    pLve[bid] = sh[3][0] + sh[3][1] + sh[3][2] + sh[3][3];
    pLc [bid] = sh[4][0] + sh[4][1] + sh[4][2] + sh[4][3];
    pReg[bid] = sh[5][0] + sh[5][1] + sh[5][2] + sh[5][3];
  }
}

// Fix-up + final combine. 256 threads: thread b walks row b's 8 segments
// applying the quadratic offset correction in f64, then block-reduce.
__global__ __launch_bounds__(THREADS) void kern2(
    const float2* __restrict__ segsum, const float* __restrict__ se2,
    const float* __restrict__ sex, const float* __restrict__ sey,
    const float* __restrict__ pLve, const float* __restrict__ pLc,
    const float* __restrict__ pReg,
    const float* __restrict__ pldv, const float* __restrict__ pldc,
    float* __restrict__ out) {
  const int tid = threadIdx.x;                         // == row b
  const int lane = tid & 63, wid = tid >> 6;

  double posAcc = 0.0, lveAcc = 0.0, lcAcc = 0.0, regAcc = 0.0;
  double Cx = 0.0, Cy = 0.0;
  const double dDT = (double)DTc;
#pragma unroll
  for (int s = 0; s < NSEG; ++s) {
    int idx = tid * NSEG + s;
    float2 ss = segsum[idx];
    posAcc += (double)se2[idx]
            + 2.0 * dDT * (Cx * (double)sex[idx] + Cy * (double)sey[idx])
            + (double)SEG_T * dDT * dDT * (Cx * Cx + Cy * Cy);
    lveAcc += (double)pLve[idx];
    lcAcc  += (double)pLc[idx];
    regAcc += (double)pReg[idx];
    Cx += (double)ss.x; Cy += (double)ss.y;
  }

  posAcc = waveReduceD(posAcc);
  lveAcc = waveReduceD(lveAcc);
  lcAcc  = waveReduceD(lcAcc);
  regAcc = waveReduceD(regAcc);
  __shared__ double sh[4][4];
  if (lane == 0) { sh[0][wid] = posAcc; sh[1][wid] = lveAcc; sh[2][wid] = lcAcc; sh[3][wid] = regAcc; }
  __syncthreads();
  if (tid == 0) {
    double pos_sq = sh[0][0] + sh[0][1] + sh[0][2] + sh[0][3];
    double vel_sq = sh[1][0] + sh[1][1] + sh[1][2] + sh[1][3];
    double lcs    = sh[2][0] + sh[2][1] + sh[2][2] + sh[2][3];
    double regs   = sh[3][0] + sh[3][1] + sh[3][2] + sh[3][3];
    const double NBT2 = (double)B_ * (double)T_ * 2.0;
    const double NBT  = (double)B_ * (double)T_;
    double lv  = (pos_sq + vel_sq) / NBT2;
    double lc  = 0.5 * lcs / NBT;
    double reg = regs / NBT;
    double ldv = (double)pldv[0], ldc = (double)pldc[0];
    double total = lv / (2.0 * exp(2.0 * ldv)) + lc / (2.0 * exp(2.0 * ldc))
                 + ldv + ldc + 0.01 * reg;
    out[0] = (float)total;
  }
}

extern "C" void kernel_launch(void* const* d_in, const int* in_sizes, int n_in,
                              void* d_out, int out_size, void* d_ws, size_t ws_size,
                              hipStream_t stream) {
  const float4* vel = (const float4*)d_in[0];
  const float4* cov = (const float4*)d_in[1];
  const float4* vgt = (const float4*)d_in[2];
  const float4* pgt = (const float4*)d_in[3];
  const float* ldv = (const float*)d_in[4];
  const float* ldc = (const float*)d_in[5];

  char* ws = (char*)d_ws;
  float2* segsum = (float2*)ws;                  // 16 KB
  float* se2  = (float*)(ws + 16 * 1024);        //  8 KB
  float* sex  = (float*)(ws + 24 * 1024);        //  8 KB
  float* sey  = (float*)(ws + 32 * 1024);        //  8 KB
  float* pLve = (float*)(ws + 40 * 1024);        //  8 KB
  float* pLc  = (float*)(ws + 48 * 1024);        //  8 KB
  float* pReg = (float*)(ws + 56 * 1024);        //  8 KB

  kern1<<<NBLK, THREADS, 0, stream>>>(vel, cov, vgt, pgt, segsum, se2, sex, sey,
                                      pLve, pLc, pReg);
  kern2<<<1, THREADS, 0, stream>>>(segsum, se2, sex, sey, pLve, pLc, pReg,
                                   ldv, ldc, (float*)d_out);
}